// Round 5
// baseline (1578.439 us; speedup 1.0000x reference)
//
#include <hip/hip_runtime.h>
#include <hip/hip_bf16.h>
#include <stdint.h>

// Problem constants (fixed by reference)
#define BATCH 16
#define NPTS  8192
#define NCH   6
#define NGRP  512   // NUM_GROUPS (FPS samples)
#define GSZ   32    // GROUP_SIZE (kNN)

#define TPB    512             // threads per block (both roles)
#define FPPT   (NPTS / TPB)    // 16 fps points per thread
#define KPPT   (NPTS / TPB)    // 16 knn candidates per thread
#define NWAVE  (TPB / 64)      // 8 waves

// ws layout (uints): [0] ticket counter; [32 + b*32] progress[b] (128 B apart)

// ---------------------------------------------------------------------------
// Fused kernel. Ticket-based role assignment (deadlock-free under ANY
// dispatch order: fps tickets 0..15 are claimed by the first-placed blocks,
// which never wait on anyone; knn tickets spin only on fps progress).
// 82000 B LDS pad -> 1 block/CU, so knn waves never share a CU with an
// fps block (protects the fps critical path from issue contention).
//
// fps numerics (bit-exact, validated rounds 2/4): d=(dx*dx+dy*dy)+dz*dz,
// contract off, fminf; argmax-first via descending-j overwrite of inv=~idx,
// u64 (value<<32|inv) max reduce.
// knn numerics (bit-exact, validated round 2): xx left-to-right,
// dot = fmaf chain (einsum), d2=(cc-2*dot)+xx, sortable-u32 map, u64 keys,
// ascending-index tie-break.
// Cross-XCD: fps publishes progress with agent-scope RELEASE store; knn
// spins with agent-scope ACQUIRE loads and reads its center with agent-scope
// atomic loads (per-XCD L2 is not coherent for plain loads).
// ---------------------------------------------------------------------------
__global__ __launch_bounds__(TPB, 2) void fused_kernel(
    const float* __restrict__ points, float* __restrict__ grouped,
    float* __restrict__ centers, unsigned* __restrict__ ws) {
#pragma clang fp contract(off)
  __shared__ union {
    struct {
      unsigned long long wslot[2][NWAVE];  // ping-pong reduce slots
      int knn_sh[GSZ];
    } s;
    char pad[82000];  // force 1 block/CU (160 KiB LDS per CU)
  } u;
  __shared__ unsigned ticket_sh;

  const int tid  = threadIdx.x;
  const int lane = tid & 63;
  const int wave = tid >> 6;

  if (tid == 0) ticket_sh = atomicAdd(ws, 1u);
  __syncthreads();
  const unsigned ticket = ticket_sh;

  if (ticket < BATCH) {
    // ================= FPS role: one block per batch =================
    const int b = (int)ticket;
    const float* P = points + (size_t)b * NPTS * NCH;
    float* C = centers + (size_t)b * NGRP * 3;
    unsigned* prog = ws + 32 + b * 32;

    float px[FPPT], py[FPPT], pz[FPPT], md[FPPT];
#pragma unroll
    for (int j = 0; j < FPPT; ++j) {
      const int i = j * TPB + tid;
      px[j] = P[i * 6 + 0];
      py[j] = P[i * 6 + 1];
      pz[j] = P[i * 6 + 2];
      md[j] = __builtin_inff();
    }

    unsigned widx = 0;  // center k-1's point index (block-uniform)
    for (int k = 1; k < NGRP; ++k) {
      // broadcast reload of center k-1 (wave-uniform address -> scalar path)
      const unsigned uw = __builtin_amdgcn_readfirstlane(widx);
      const float lx = P[uw * 6 + 0];
      const float ly = P[uw * 6 + 1];
      const float lz = P[uw * 6 + 2];
      if (tid == 0) {  // deferred store of center k-1 + periodic publish
        C[(k - 1) * 3 + 0] = lx;
        C[(k - 1) * 3 + 1] = ly;
        C[(k - 1) * 3 + 2] = lz;
        if ((k & 7) == 0)
          __hip_atomic_store(prog, (unsigned)k, __ATOMIC_RELEASE,
                             __HIP_MEMORY_SCOPE_AGENT);
      }

      // inner: min-dist update + per-thread max (bit-exact ref order)
      float bestv = -__builtin_inff();
#pragma unroll
      for (int j = 0; j < FPPT; ++j) {
        const float dx = px[j] - lx;
        const float dy = py[j] - ly;
        const float dz = pz[j] - lz;
        const float d  = (dx * dx + dy * dy) + dz * dz;
        md[j] = fminf(md[j], d);
        bestv = fmaxf(bestv, md[j]);
      }
      // first index attaining bestv (inv decreases with j)
      unsigned invbest = 0;
#pragma unroll
      for (int j = FPPT - 1; j >= 0; --j)
        invbest = (md[j] == bestv) ? ~(unsigned)(j * TPB + tid) : invbest;

      unsigned long long key =
          ((unsigned long long)__float_as_uint(bestv) << 32) | invbest;
#pragma unroll
      for (int off = 32; off >= 1; off >>= 1) {
        const unsigned long long o = __shfl_xor(key, off);
        key = key > o ? key : o;
      }
      if (lane == 0) u.s.wslot[k & 1][wave] = key;
      __syncthreads();  // the only barrier per step

      unsigned long long kk = u.s.wslot[k & 1][lane & 7];
#pragma unroll
      for (int off = 4; off >= 1; off >>= 1) {
        const unsigned long long o = __shfl_xor(kk, off);
        kk = kk > o ? kk : o;
      }
      widx = ~(unsigned)(kk & 0xFFFFFFFFull);
    }
    // final center (index widx after step 511)
    if (tid == 0) {
      const unsigned uw = widx;
      C[(NGRP - 1) * 3 + 0] = P[uw * 6 + 0];
      C[(NGRP - 1) * 3 + 1] = P[uw * 6 + 1];
      C[(NGRP - 1) * 3 + 2] = P[uw * 6 + 2];
      __hip_atomic_store(prog, (unsigned)NGRP, __ATOMIC_RELEASE,
                         __HIP_MEMORY_SCOPE_AGENT);
    }
  } else {
    // ================= kNN role: one block per (batch, group) =============
    const unsigned gid = ticket - BATCH;
    const int b = (int)(gid >> 9);
    const int g = (int)(gid & 511);
    const float* P = points + (size_t)b * NPTS * NCH;
    const float* cen = centers + ((size_t)b * NGRP + g) * 3;
    unsigned* prog = ws + 32 + b * 32;

    if (tid == 0) {  // spin until center g is published
      while (__hip_atomic_load(prog, __ATOMIC_ACQUIRE,
                               __HIP_MEMORY_SCOPE_AGENT) < (unsigned)(g + 1))
        __builtin_amdgcn_s_sleep(16);
    }
    __syncthreads();

    // center via agent-scope atomic loads (fresh across XCDs)
    const float cx = __hip_atomic_load(&cen[0], __ATOMIC_RELAXED,
                                       __HIP_MEMORY_SCOPE_AGENT);
    const float cy = __hip_atomic_load(&cen[1], __ATOMIC_RELAXED,
                                       __HIP_MEMORY_SCOPE_AGENT);
    const float cz = __hip_atomic_load(&cen[2], __ATOMIC_RELAXED,
                                       __HIP_MEMORY_SCOPE_AGENT);
    const float cc = (cx * cx + cy * cy) + cz * cz;

    unsigned long long keys[KPPT];
#pragma unroll
    for (int j = 0; j < KPPT; ++j) {
      const int i = j * TPB + tid;
      const float x = P[i * 6 + 0];
      const float y = P[i * 6 + 1];
      const float z = P[i * 6 + 2];
      const float xx  = (x * x + y * y) + z * z;
      const float dot = fmaf(cz, z, fmaf(cy, y, cx * x));  // einsum fma chain
      const float d2  = (cc - 2.0f * dot) + xx;
      unsigned v = __float_as_uint(d2);
      v = (v & 0x80000000u) ? ~v : (v | 0x80000000u);  // sortable map
      keys[j] = ((unsigned long long)v << 32) | (unsigned long long)(unsigned)i;
    }
    unsigned long long lmin = keys[0];
#pragma unroll
    for (int j = 1; j < KPPT; ++j) lmin = lmin < keys[j] ? lmin : keys[j];

    for (int j = 0; j < GSZ; ++j) {
      unsigned long long v = lmin;
#pragma unroll
      for (int off = 32; off >= 1; off >>= 1) {
        const unsigned long long o = __shfl_xor(v, off);
        v = v < o ? v : o;
      }
      if (lane == 0) u.s.wslot[j & 1][wave] = v;
      __syncthreads();
      unsigned long long w = u.s.wslot[j & 1][lane & 7];
#pragma unroll
      for (int off = 4; off >= 1; off >>= 1) {
        const unsigned long long o = __shfl_xor(w, off);
        w = w < o ? w : o;
      }
      const int widx = (int)(unsigned)(w & 0xFFFFFFFFull);
      if (tid == (widx & (TPB - 1))) {  // owner removes winner, rebuilds min
#pragma unroll
        for (int s = 0; s < KPPT; ++s)
          if ((unsigned)(keys[s] & 0xFFFFFFFFull) == (unsigned)widx)
            keys[s] = ~0ull;
        lmin = keys[0];
#pragma unroll
        for (int s = 1; s < KPPT; ++s) lmin = lmin < keys[s] ? lmin : keys[s];
      }
      if (tid == 0) u.s.knn_sh[j] = widx;
    }
    __syncthreads();

    // gather + center-relative xyz; 192 output floats per group
    float* outg = grouped + ((size_t)b * NGRP + g) * GSZ * NCH;
    if (tid < GSZ * NCH) {
      const int n = tid / 6, c = tid % 6;
      const int idx = u.s.knn_sh[n];
      float v2 = P[idx * 6 + c];
      if (c < 3) {
        const float cv = (c == 0) ? cx : (c == 1) ? cy : cz;
        v2 = v2 - cv;  // exact ref subtract
      }
      outg[tid] = v2;
    }
  }
}

extern "C" void kernel_launch(void* const* d_in, const int* in_sizes, int n_in,
                              void* d_out, int out_size, void* d_ws, size_t ws_size,
                              hipStream_t stream) {
  const float* points = (const float*)d_in[0];
  float* out = (float*)d_out;
  float* grouped = out;                                        // [16,512,32,6]
  float* centers = out + (size_t)BATCH * NGRP * GSZ * NCH;     // [16,512,3]
  unsigned* ws = (unsigned*)d_ws;

  // zero ticket counter + progress flags (ws is poisoned 0xAA pre-launch)
  hipMemsetAsync(ws, 0, 4096, stream);
  fused_kernel<<<BATCH + BATCH * NGRP, TPB, 0, stream>>>(points, grouped,
                                                         centers, ws);
}

// Round 7
// 839.719 us; speedup vs baseline: 1.8797x; 1.8797x over previous
//
#include <hip/hip_runtime.h>
#include <hip/hip_bf16.h>
#include <stdint.h>

// Problem constants (fixed by reference)
#define BATCH 16
#define NPTS  8192
#define NCH   6
#define NGRP  512   // NUM_GROUPS (FPS samples)
#define GSZ   32    // GROUP_SIZE (kNN)

#define FPS_T   1024              // 16 waves, 4/SIMD
#define FPS_PPT 8                 // contiguous: idx = tid*8 + j
#define FPS_W   16

typedef float v2f __attribute__((ext_vector_type(2)));

// DPP ctrl encodings (gfx9+): row_shr:N = 0x110|N, row_bcast15/31 = 0x142/0x143
// update_dpp requires ctrl as an ICE -> template parameter.
template <int CTRL>
__device__ __forceinline__ float dpp_max_f32(float v) {
  // bound_ctrl=1 -> invalid source lanes read 0; all reduced values are >= 0
  // (squared distances; -inf only pre-update), and 0 never exceeds a real
  // wave max here since md >= 0, so max-with-0 is identity-safe.
  const int t =
      __builtin_amdgcn_update_dpp(0, __float_as_int(v), CTRL, 0xf, 0xf, true);
  return fmaxf(v, __int_as_float(t));
}

// ---------------------------------------------------------------------------
// Kernel 1: farthest point sampling. One block per batch (16 CUs active).
// Round-7 structure (= round-6 design, compile-fixed): one barrier/step,
// DPP-based reduces (no DS-pipe shuffles), ballot index resolution under
// CONTIGUOUS point mapping (idx = tid*8+j, lane order == index order),
// speculative coord fetch overlapping the level-2 reduce.
//
// Numerics (bit-exact, validated rounds 2/4): d = (dx*dx+dy*dy)+dz*dz,
// contract off (pk ops are per-element IEEE, fusion suppressed), fminf
// running min. argmax-first == value-max then min index; min index ==
// first matching lane (contiguous mapping), then min j within the lane
// (descending-j overwrite). Cross-wave ties -> min wave == first matching
// slot in the level-2 ballot.
// ---------------------------------------------------------------------------
__global__ __launch_bounds__(FPS_T, 1) void fps_kernel(
    const float* __restrict__ points, float* __restrict__ centers) {
#pragma clang fp contract(off)
  const int b    = blockIdx.x;
  const int tid  = threadIdx.x;
  const int lane = tid & 63;
  const int wave = tid >> 6;
  const float* P = points + (size_t)b * NPTS * NCH;
  float* C = centers + (size_t)b * NGRP * 3;

  __shared__ float cache[NPTS * 3];                    // xyz cache, 96 KiB
  __shared__ unsigned long long wslot[2][FPS_W];       // ping-pong slots

  v2f px[4], py[4], pz[4], md[4];
  {
    float* fx = (float*)px; float* fy = (float*)py; float* fz = (float*)pz;
#pragma unroll
    for (int j = 0; j < FPS_PPT; ++j) {
      const int i = tid * FPS_PPT + j;   // contiguous mapping
      const float x = P[i * 6 + 0];
      const float y = P[i * 6 + 1];
      const float z = P[i * 6 + 2];
      fx[j] = x; fy[j] = y; fz[j] = z;
      cache[i * 3 + 0] = x;
      cache[i * 3 + 1] = y;
      cache[i * 3 + 2] = z;
    }
#pragma unroll
    for (int j = 0; j < 4; ++j) md[j] = (v2f){__builtin_inff(), __builtin_inff()};
  }
  __syncthreads();  // cache ready

  // current center = point 0
  float lx = cache[0], ly = cache[1], lz = cache[2];

  for (int k = 1; k < NGRP; ++k) {
    if (tid == 0) {  // store center k-1 (uniform regs, off critical path)
      C[(k - 1) * 3 + 0] = lx; C[(k - 1) * 3 + 1] = ly; C[(k - 1) * 3 + 2] = lz;
    }

    // ---- inner: packed min-dist update + per-thread max ----
    const v2f vlx = {lx, lx}, vly = {ly, ly}, vlz = {lz, lz};
    v2f b2 = {-__builtin_inff(), -__builtin_inff()};
#pragma unroll
    for (int j = 0; j < 4; ++j) {
      const v2f dx = px[j] - vlx;
      const v2f dy = py[j] - vly;
      const v2f dz = pz[j] - vlz;
      const v2f d  = (dx * dx + dy * dy) + dz * dz;  // ref op order, no fma
      md[j] = __builtin_elementwise_min(md[j], d);
      b2 = __builtin_elementwise_max(b2, md[j]);
    }
    const float bestv = fmaxf(b2.x, b2.y);

    // first (min) index attaining bestv: descending scan ends at min j
    unsigned idxbest = 0;
#pragma unroll
    for (int j = 3; j >= 0; --j) {
      idxbest = (md[j].y == bestv) ? (unsigned)(tid * 8 + 2 * j + 1) : idxbest;
      idxbest = (md[j].x == bestv) ? (unsigned)(tid * 8 + 2 * j)     : idxbest;
    }

    // ---- level-1: wave max via DPP (VALU only) ----
    float wv = bestv;
    wv = dpp_max_f32<0x111>(wv); wv = dpp_max_f32<0x112>(wv);
    wv = dpp_max_f32<0x114>(wv); wv = dpp_max_f32<0x118>(wv);
    wv = dpp_max_f32<0x142>(wv); wv = dpp_max_f32<0x143>(wv);
    const float wvmax =
        __int_as_float(__builtin_amdgcn_readlane(__float_as_int(wv), 63));

    // owner = first lane attaining wave max (== min index owner)
    const unsigned long long m1 = __ballot(bestv == wvmax);
    const int owner = (int)__builtin_ctzll(m1);
    if (lane == owner)
      wslot[k & 1][wave] =
          ((unsigned long long)__float_as_uint(wvmax) << 32) | idxbest;
    __syncthreads();  // the only barrier per step

    // ---- level-2: 16 slots, row-replicated; DPP row max + ballot ----
    const unsigned long long slot = wslot[k & 1][lane & 15];
    const unsigned sidx = (unsigned)(slot & 0xFFFFFFFFull);
    const float    sval = __uint_as_float((unsigned)(slot >> 32));
    // speculative candidate coords (overlaps the DPP reduce below)
    const float ccx = cache[sidx * 3 + 0];
    const float ccy = cache[sidx * 3 + 1];
    const float ccz = cache[sidx * 3 + 2];

    float r = sval;
    r = dpp_max_f32<0x111>(r); r = dpp_max_f32<0x112>(r);
    r = dpp_max_f32<0x114>(r); r = dpp_max_f32<0x118>(r);
    const float gmax =
        __int_as_float(__builtin_amdgcn_readlane(__float_as_int(r), 15));
    const int sstar =
        (int)__builtin_ctzll(__ballot(sval == gmax) & 0xFFFFull);  // min wave
    lx = __int_as_float(__builtin_amdgcn_readlane(__float_as_int(ccx), sstar));
    ly = __int_as_float(__builtin_amdgcn_readlane(__float_as_int(ccy), sstar));
    lz = __int_as_float(__builtin_amdgcn_readlane(__float_as_int(ccz), sstar));
  }
  if (tid == 0) {  // final center
    C[(NGRP - 1) * 3 + 0] = lx;
    C[(NGRP - 1) * 3 + 1] = ly;
    C[(NGRP - 1) * 3 + 2] = lz;
  }
}

// ---------------------------------------------------------------------------
// Kernel 2: 32-NN per (batch, group) + gather + center-relative output.
// (round-2 version, validated bit-exact; untouched this round)
// ---------------------------------------------------------------------------
__global__ __launch_bounds__(256) void knn_kernel(
    const float* __restrict__ points, const float* __restrict__ centers,
    float* __restrict__ grouped) {
#pragma clang fp contract(off)
  const int g    = blockIdx.x;
  const int b    = blockIdx.y;
  const int tid  = threadIdx.x;
  const int lane = tid & 63;
  const int wave = tid >> 6;
  const float* P   = points + (size_t)b * NPTS * NCH;
  const float* cen = centers + ((size_t)b * NGRP + g) * 3;
  const float cx = cen[0], cy = cen[1], cz = cen[2];
  const float cc = (cx * cx + cy * cy) + cz * cz;

  unsigned long long keys[32];
  for (int j = 0; j < 32; ++j) {
    const int i = j * 256 + tid;
    const float x = P[i * 6 + 0];
    const float y = P[i * 6 + 1];
    const float z = P[i * 6 + 2];
    const float xx  = (x * x + y * y) + z * z;
    const float dot = fmaf(cz, z, fmaf(cy, y, cx * x));  // einsum fma chain
    const float d2  = (cc - 2.0f * dot) + xx;
    unsigned u = __float_as_uint(d2);
    u = (u & 0x80000000u) ? ~u : (u | 0x80000000u);  // sortable map
    keys[j] = ((unsigned long long)u << 32) | (unsigned long long)(unsigned)i;
  }
  unsigned long long lmin = keys[0];
  for (int j = 1; j < 32; ++j) lmin = lmin < keys[j] ? lmin : keys[j];

  __shared__ unsigned long long wred[2][4];
  __shared__ int knn_sh[GSZ];

  for (int j = 0; j < GSZ; ++j) {
    unsigned long long v = lmin;
    for (int off = 32; off >= 1; off >>= 1) {
      const unsigned long long o = __shfl_down(v, off);
      v = v < o ? v : o;
    }
    if (lane == 0) wred[j & 1][wave] = v;
    __syncthreads();
    unsigned long long w = wred[j & 1][0];
    for (int q2 = 1; q2 < 4; ++q2) {
      const unsigned long long o = wred[j & 1][q2];
      w = w < o ? w : o;
    }
    const int widx = (int)(unsigned)(w & 0xFFFFFFFFull);
    if (tid == (widx & 255)) {  // owner removes winner, rebuilds local min
      for (int s = 0; s < 32; ++s)
        if ((unsigned)(keys[s] & 0xFFFFFFFFull) == (unsigned)widx)
          keys[s] = ~0ull;
      lmin = keys[0];
      for (int s = 1; s < 32; ++s) lmin = lmin < keys[s] ? lmin : keys[s];
    }
    if (tid == 0) knn_sh[j] = widx;
  }
  __syncthreads();

  // gather + center-relative xyz; 192 output floats per group
  float* outg = grouped + ((size_t)b * NGRP + g) * GSZ * NCH;
  for (int t = tid; t < GSZ * NCH; t += 256) {
    const int n = t / 6, c = t % 6;
    const int idx = knn_sh[n];
    float v = P[idx * 6 + c];
    if (c < 3) v = v - cen[c];  // exact ref subtract
    outg[t] = v;
  }
}

extern "C" void kernel_launch(void* const* d_in, const int* in_sizes, int n_in,
                              void* d_out, int out_size, void* d_ws, size_t ws_size,
                              hipStream_t stream) {
  const float* points = (const float*)d_in[0];
  float* out = (float*)d_out;
  float* grouped = out;                                        // [16,512,32,6]
  float* centers = out + (size_t)BATCH * NGRP * GSZ * NCH;     // [16,512,3]

  fps_kernel<<<BATCH, FPS_T, 0, stream>>>(points, centers);
  knn_kernel<<<dim3(NGRP, BATCH), 256, 0, stream>>>(points, centers, grouped);
}